// Round 1
// baseline (49.798 us; speedup 1.0000x reference)
//
#include <hip/hip_runtime.h>

#define BB 16
#define CC 64
#define HH 64
#define WW 64
#define OO 128

// Block: 256 threads = 4 rows x 64 cols (one wave per image row).
// Grid: 8 o-chunks * 16 h-strips * 16 batches = 2048 blocks.
__global__ __launch_bounds__(256) void minimax_conv_kernel(
    const float* __restrict__ x, const float* __restrict__ w1,
    const float* __restrict__ w2, const int* __restrict__ conn,
    float* __restrict__ out)
{
    const int tid  = threadIdx.x;
    const int w    = tid & 63;        // lane -> column (coalesced)
    const int hloc = tid >> 6;        // wave id within block -> row
    int bid = blockIdx.x;
    const int ochunk = bid & 7;       // 8 chunks of 16 output channels
    bid >>= 3;
    const int h0 = (bid & 15) * 4;
    const int b  = bid >> 4;
    const int h  = h0 + hloc;
    // force wave-uniform row into SGPR so tap addresses stay scalar
    const int hs = __builtin_amdgcn_readfirstlane(h);

    // per-lane clamped columns for j-1 in {-1, 0, +1}  (edge-replicate pad)
    const int colm = (w == 0)  ? 0  : (w - 1);
    const int colp = (w == 63) ? 63 : (w + 1);

    const float* xb = x + (size_t)b * (CC * HH * WW);

    for (int oi = 0; oi < 16; ++oi) {
        const int o = ochunk * 16 + oi;

        float d[9];
        #pragma unroll
        for (int t = 0; t < 9; ++t) {
            const int v = conn[o * 9 + t];     // wave-uniform -> s_load
            const int c = v / 9;
            const int r = v - c * 9;
            const int i = r / 3;               // 0..2 kernel row
            const int j = r - i * 3;           // 0..2 kernel col
            int row = hs + i - 1;
            row = row < 0 ? 0 : (row > HH - 1 ? HH - 1 : row);
            const int col = (j == 0) ? colm : ((j == 1) ? w : colp);
            const float g = xb[(c * HH + row) * WW + col];  // coalesced per wave
            d[t] = fabsf(g - w1[o * 9 + t]);
        }
        const float e0 = fmaxf(fmaxf(d[0], d[1]), d[2]);
        const float e1 = fmaxf(fmaxf(d[3], d[4]), d[5]);
        const float e2 = fmaxf(fmaxf(d[6], d[7]), d[8]);
        const float m0 = fabsf(e0 - w2[o * 3 + 0]);
        const float m1 = fabsf(e1 - w2[o * 3 + 1]);
        const float m2 = fabsf(e2 - w2[o * 3 + 2]);
        const float res = fminf(fminf(m0, m1), m2);

        out[(((size_t)b * OO + o) * HH + h) * WW + w] = res;
    }
}

extern "C" void kernel_launch(void* const* d_in, const int* in_sizes, int n_in,
                              void* d_out, int out_size, void* d_ws, size_t ws_size,
                              hipStream_t stream) {
    const float* x    = (const float*)d_in[0];
    const float* w1   = (const float*)d_in[1];
    const float* w2   = (const float*)d_in[2];
    const int*   conn = (const int*)d_in[3];
    float* out = (float*)d_out;

    const int blocks = 8 * 16 * BB;   // o-chunks * h-strips * batch = 2048
    minimax_conv_kernel<<<blocks, 256, 0, stream>>>(x, w1, w2, conn, out);
}